// Round 11
// baseline (2782.572 us; speedup 1.0000x reference)
//
#include <hip/hip_runtime.h>
#include <hip/hip_bf16.h>
#include <cstdint>
#include <cstddef>

typedef __bf16 bf16_t;
typedef __bf16 bf16x4 __attribute__((ext_vector_type(4)));
typedef __bf16 bf16x8 __attribute__((ext_vector_type(8)));
typedef float  f32x4  __attribute__((ext_vector_type(4)));

#define L_DIM 2048
#define N_DIM 8
#define E_DIM 2048
#define H_DIM 8192
#define T_DIM (L_DIM * N_DIM)   // 16384 tokens

// ---------------------------------------------------------------------------
__global__ __launch_bounds__(256) void cvt_f32_bf16(const float* __restrict__ in,
                                                    bf16_t* __restrict__ out,
                                                    int n4) {
    int stride = gridDim.x * blockDim.x;
    for (int i = blockIdx.x * blockDim.x + threadIdx.x; i < n4; i += stride) {
        float4 v = *(const float4*)(in + (size_t)i * 4);
        bf16x4 o;
        o[0] = (bf16_t)v.x; o[1] = (bf16_t)v.y;
        o[2] = (bf16_t)v.z; o[3] = (bf16_t)v.w;
        *(bf16x4*)(out + (size_t)i * 4) = o;
    }
}

// ---------------------------------------------------------------------------
__device__ __forceinline__ float fast_gelu(float x) {
    float x2 = x * x;
    float w  = x * __builtin_fmaf(0.1029456f, x2, 2.3022618f);
    w = fminf(w, 60.0f);
    float s = __builtin_amdgcn_exp2f(w);
    float r = __builtin_amdgcn_rcpf(s + 1.0f);
    return x * s * r;
}

// ---------------------------------------------------------------------------
// Persistent 256x256 GEMM = R9 skeleton (4 phases, 4 barriers, stage slot u+1
// only: B0@ph0,B1@ph1,A0@ph2,A1@ph3; vmcnt(2) at ph0-end and ph3-end) plus
// ONE change: READ-AHEAD. ph3 reads next iter's B(8)+A01(4) AFTER its
// barrier (data guaranteed landed by the vmcnt(2)+BAR), so the LDS drain of
// the big read burst hides under MFMA m67; phases 0-2 read only 4 A-frags.
// Counted lgkmcnt before each MFMA = #reads allowed to float:
//   ph0: lgkm(4)  (af23 floats; bf+af01 from ph3(u-1) must be done)
//   ph1: lgkm(4)  (af45 floats; af23 done)
//   ph2: lgkm(4)  (af67 floats; af45 done)
//   ph3: lgkm(12) (bf(u+1)+af01(u+1) float; af67 done)
// vmcnt derivation (stage order B0,B1,A0,A1, 2 gll each):
//   ph0-end: outstanding = A1(u)[2] + B0(u+1)[2] -> vmcnt(2) drains A1(u)
//            before ph1's af45 (rows 128..191) reads.
//   ph3-end: outstanding = B0,B1,A0,A1(u+1)[8] -> vmcnt(2) drains all but
//            A1(u+1) before the post-BAR reads of bf(u+1)+af01(u+1).
// Frag registers rotate: af_a/af_b alternate per phase; bfP/bfQ per K-iter
// parity (t-loop unrolled by 2, NT even). Tail reads hit the dead parity
// buffer (dummy-staged), values never consumed.
// ---------------------------------------------------------------------------
template <bool GELU_OUT, int LG_NT, int LG_TN, int LG_NTILE, int KDIM, int NDIM>
__global__ __launch_bounds__(512, 2) void gemm256(const bf16_t* __restrict__ Am,
                                                  const bf16_t* __restrict__ Bm,
                                                  const float* __restrict__ bias,
                                                  void* __restrict__ Cout) {
    extern __shared__ char lds[];
    constexpr int NT    = 1 << LG_NT;      // K-tiles per output tile (KDIM/64)
    constexpr int ntile = 1 << LG_NTILE;   // output tiles per block
    constexpr int U     = ntile << LG_NT;  // total flat K-iterations

    const int tid  = threadIdx.x;
    const int lane = tid & 63;
    const int wid  = tid >> 6;
    const int wr   = wid >> 2;   // 0..1
    const int wc   = wid & 3;    // 0..3

    // XCD-aware bijective swizzle over the fixed 256-block grid (q = 32)
    const int wgb = (blockIdx.x & 7) * 32 + (blockIdx.x >> 3);
    const int g0  = wgb << LG_NTILE;

    // staging lane geometry: row_in_half = wid*8 + (lane>>3), phys slot = lane&7,
    // pre-swizzled logical col slot = (lane&7) ^ (row&7)  [row&7 == lane>>3]
    const int srow  = wid * 8 + (lane >> 3);
    const int scol8 = ((lane & 7) ^ (lane >> 3)) * 8;

    auto STAGE_F = [&](int isB, int half, int slot) {
        const int us  = (slot < U) ? slot : (U - 1);       // clamp tail (dummy)
        const int ti_ = us >> LG_NT;
        const int kt_ = us & (NT - 1);
        const int g_  = g0 + ti_;
        const size_t base_ = (size_t)(isB ? (g_ & ((1 << LG_TN) - 1)) : (g_ >> LG_TN)) << 8;
        // parity from UNCLAMPED slot -> dummies land in the dead buffer
        const unsigned reg_ = (unsigned)(((slot & 1) << 16) | (isB << 15) | (half << 14));
        const bf16_t* s0 = (isB ? Bm : Am)
                         + (base_ + (size_t)(half * 128 + srow)) * (size_t)KDIM
                         + (size_t)((kt_ << 6) + scol8);
        __builtin_amdgcn_global_load_lds(
            (const __attribute__((address_space(1))) void*)s0,
            (__attribute__((address_space(3))) void*)(lds + reg_ + (unsigned)(wid * 1024)),
            16, 0, 0);
        __builtin_amdgcn_global_load_lds(
            (const __attribute__((address_space(1))) void*)(s0 + (size_t)64 * KDIM),
            (__attribute__((address_space(3))) void*)(lds + reg_ + (unsigned)((8 + wid) * 1024)),
            16, 0, 0);
    };

    // M-frag m of wave wr -> tile row (m>>1)*64 + wr*32 + (m&1)*16
    auto ldsA = [&](unsigned bufo, int m, int kk) -> bf16x8 {
        const int row  = (m >> 1) * 64 + wr * 32 + (m & 1) * 16 + (lane & 15);
        const int slot = ((kk << 2) + (lane >> 4)) ^ (lane & 7);
        return *(const bf16x8*)(lds + bufo + row * 128 + slot * 16);
    };
    auto ldsB = [&](unsigned bufo, int n, int kk) -> bf16x8 {
        const int row  = wc * 64 + n * 16 + (lane & 15);
        const int slot = ((kk << 2) + (lane >> 4)) ^ (lane & 7);
        return *(const bf16x8*)(lds + bufo + 32768 + row * 128 + slot * 16);
    };

#define RD_A(dst, P, M0) do {                                                   \
        dst[0][0] = ldsA((P) * 65536u, (M0),     0);                            \
        dst[0][1] = ldsA((P) * 65536u, (M0),     1);                            \
        dst[1][0] = ldsA((P) * 65536u, (M0) + 1, 0);                            \
        dst[1][1] = ldsA((P) * 65536u, (M0) + 1, 1); } while (0)
#define RD_B(dst, P) do {                                                       \
        _Pragma("unroll") for (int n_ = 0; n_ < 4; ++n_) {                      \
            dst[n_][0] = ldsB((P) * 65536u, n_, 0);                             \
            dst[n_][1] = ldsB((P) * 65536u, n_, 1); } } while (0)
#define MFMA16(AB, AF, BF) do {                                                 \
        _Pragma("unroll") for (int mm = 0; mm < 2; ++mm)                        \
        _Pragma("unroll") for (int n_ = 0; n_ < 4; ++n_)                        \
        _Pragma("unroll") for (int kk = 0; kk < 2; ++kk)                        \
            acc[(AB) + mm][n_] = __builtin_amdgcn_mfma_f32_16x16x32_bf16(       \
                AF[mm][kk], BF[n_][kk], acc[(AB) + mm][n_], 0, 0, 0); } while (0)

// One K-iteration. PARL = u&1 literal; BC = B frags of iter u, BN = of u+1.
#define KITER(U_, PARL, BC, BN) do {                                            \
        const int u_ = (U_);                                                    \
        /* ph0: stage B0(u+1); read af23(u); MFMA m01 on af_a */                \
        STAGE_F(1, 0, u_ + 1);                                                  \
        RD_A(af_b, PARL, 2);                                                    \
        asm volatile("s_waitcnt vmcnt(2)" ::: "memory");                        \
        __builtin_amdgcn_s_barrier();                                           \
        asm volatile("s_waitcnt lgkmcnt(4)" ::: "memory");                      \
        __builtin_amdgcn_s_setprio(1);                                          \
        MFMA16(0, af_a, BC);                                                    \
        __builtin_amdgcn_s_setprio(0);                                          \
        /* ph1: stage B1(u+1); read af45(u); MFMA m23 on af_b */                \
        STAGE_F(1, 1, u_ + 1);                                                  \
        RD_A(af_a, PARL, 4);                                                    \
        __builtin_amdgcn_s_barrier();                                           \
        asm volatile("s_waitcnt lgkmcnt(4)" ::: "memory");                      \
        __builtin_amdgcn_s_setprio(1);                                          \
        MFMA16(2, af_b, BC);                                                    \
        __builtin_amdgcn_s_setprio(0);                                          \
        /* ph2: stage A0(u+1); read af67(u); MFMA m45 on af_a */                \
        STAGE_F(0, 0, u_ + 1);                                                  \
        RD_A(af_b, PARL, 6);                                                    \
        __builtin_amdgcn_s_barrier();                                           \
        asm volatile("s_waitcnt lgkmcnt(4)" ::: "memory");                      \
        __builtin_amdgcn_s_setprio(1);                                          \
        MFMA16(4, af_a, BC);                                                    \
        __builtin_amdgcn_s_setprio(0);                                          \
        /* ph3: stage A1(u+1); vmcnt+BAR; READ-AHEAD bf(u+1)+af01(u+1); */      \
        /*      MFMA m67 on af_b (their drain hides under it) */                \
        STAGE_F(0, 1, u_ + 1);                                                  \
        asm volatile("s_waitcnt vmcnt(2)" ::: "memory");                        \
        __builtin_amdgcn_s_barrier();                                           \
        RD_B(BN, (PARL) ^ 1);                                                   \
        RD_A(af_a, (PARL) ^ 1, 0);                                              \
        asm volatile("s_waitcnt lgkmcnt(12)" ::: "memory");                     \
        __builtin_amdgcn_s_setprio(1);                                          \
        MFMA16(6, af_b, BC);                                                    \
        __builtin_amdgcn_s_setprio(0);                                          \
    } while (0)

    f32x4  acc[8][4] = {};
    bf16x8 bfP[4][2], bfQ[4][2], af_a[2][2], af_b[2][2];

    // Prologue: stage slot 0 completely, drain, publish, pre-read bf(0)+af01(0).
    STAGE_F(1, 0, 0); STAGE_F(1, 1, 0); STAGE_F(0, 0, 0); STAGE_F(0, 1, 0);
    asm volatile("s_waitcnt vmcnt(0)" ::: "memory");
    __builtin_amdgcn_s_barrier();
    RD_B(bfP, 0);
    RD_A(af_a, 0, 0);

    for (int ti = 0; ti < ntile; ++ti) {
        const int ub = ti << LG_NT;
        for (int t = 0; t < NT; t += 2) {
            KITER(ub + t,     0, bfP, bfQ);
            KITER(ub + t + 1, 1, bfQ, bfP);
        }

        // ---- per-tile epilogue (reg-only; next tile's bf/af01 already read) ----
        const int g = g0 + ti;
        const size_t rowBase = (size_t)(g >> LG_TN) << 8;
        const size_t colBase = (size_t)(g & ((1 << LG_TN) - 1)) << 8;
        const int orow = (lane >> 4) * 4;
        const int ocol = lane & 15;
#pragma unroll
        for (int m = 0; m < 8; ++m) {
            const size_t rb = rowBase + (size_t)((m >> 1) * 64 + wr * 32 + (m & 1) * 16 + orow);
#pragma unroll
            for (int n = 0; n < 4; ++n) {
                const size_t col = colBase + (size_t)(wc * 64 + n * 16 + ocol);
                const float bv = bias[col];
#pragma unroll
                for (int j = 0; j < 4; ++j) {
                    float v = acc[m][n][j] + bv;
                    if constexpr (GELU_OUT) {
                        ((bf16_t*)Cout)[(rb + j) * (size_t)NDIM + col] = (bf16_t)fast_gelu(v);
                    } else {
                        ((float*)Cout)[(rb + j) * (size_t)NDIM + col] = v;
                    }
                }
                acc[m][n] = (f32x4){0.f, 0.f, 0.f, 0.f};
            }
        }
    }
    asm volatile("s_waitcnt vmcnt(0)" ::: "memory");   // drain tail dummy loads

#undef KITER
#undef MFMA16
#undef RD_B
#undef RD_A
}

// ---------------------------------------------------------------------------
extern "C" void kernel_launch(void* const* d_in, const int* in_sizes, int n_in,
                              void* d_out, int out_size, void* d_ws, size_t ws_size,
                              hipStream_t stream) {
    const float* x  = (const float*)d_in[0];  // [16384, 2048]
    const float* p1 = (const float*)d_in[1];  // [8192, 2048]
    const float* b1 = (const float*)d_in[2];  // [8192]
    const float* p2 = (const float*)d_in[3];  // [2048, 8192]
    const float* b2 = (const float*)d_in[4];  // [2048]
    // d_in[5] = gate_w, unused (routing is identity on the output)
    float* out = (float*)d_out;

    char* ws = (char*)d_ws;
    bf16_t* xb  = (bf16_t*)(ws);                          // 64 MB
    bf16_t* p1b = (bf16_t*)(ws + ((size_t)64 << 20));     // 32 MB
    bf16_t* p2b = (bf16_t*)(ws + ((size_t)96 << 20));     // 32 MB
    bf16_t* h   = (bf16_t*)(ws + ((size_t)128 << 20));    // 256 MB

    // GEMM1: [T,E] x [H,E]^T -> h.  2048 tiles = 256 blocks x 8 tiles.
    auto g1 = gemm256<true, 5, 5, 3, E_DIM, H_DIM>;
    // GEMM2: [T,H] x [E,H]^T -> out. 512 tiles = 256 blocks x 2 tiles.
    auto g2 = gemm256<false, 7, 3, 1, H_DIM, E_DIM>;

    (void)hipFuncSetAttribute((const void*)g1,
                              hipFuncAttributeMaxDynamicSharedMemorySize, 131072);
    (void)hipFuncSetAttribute((const void*)g2,
                              hipFuncAttributeMaxDynamicSharedMemorySize, 131072);

    cvt_f32_bf16<<<2048, 256, 0, stream>>>(x,  xb,  (T_DIM * E_DIM) / 4);
    cvt_f32_bf16<<<1024, 256, 0, stream>>>(p1, p1b, (H_DIM * E_DIM) / 4);
    cvt_f32_bf16<<<1024, 256, 0, stream>>>(p2, p2b, (E_DIM * H_DIM) / 4);

    g1<<<256, 512, 131072, stream>>>(xb, p1b, b1, (void*)h);
    g2<<<256, 512, 131072, stream>>>(h, p2b, b2, (void*)out);
}

// Round 12
// 1124.128 us; speedup vs baseline: 2.4753x; 2.4753x over previous
//
#include <hip/hip_runtime.h>
#include <hip/hip_bf16.h>
#include <cstdint>
#include <cstddef>

typedef __bf16 bf16_t;
typedef __bf16 bf16x4 __attribute__((ext_vector_type(4)));
typedef __bf16 bf16x8 __attribute__((ext_vector_type(8)));
typedef float  f32x4  __attribute__((ext_vector_type(4)));

#define L_DIM 2048
#define N_DIM 8
#define E_DIM 2048
#define H_DIM 8192
#define T_DIM (L_DIM * N_DIM)   // 16384 tokens

// ---------------------------------------------------------------------------
__global__ __launch_bounds__(256) void cvt_f32_bf16(const float* __restrict__ in,
                                                    bf16_t* __restrict__ out,
                                                    int n4) {
    int stride = gridDim.x * blockDim.x;
    for (int i = blockIdx.x * blockDim.x + threadIdx.x; i < n4; i += stride) {
        float4 v = *(const float4*)(in + (size_t)i * 4);
        bf16x4 o;
        o[0] = (bf16_t)v.x; o[1] = (bf16_t)v.y;
        o[2] = (bf16_t)v.z; o[3] = (bf16_t)v.w;
        *(bf16x4*)(out + (size_t)i * 4) = o;
    }
}

// ---------------------------------------------------------------------------
__device__ __forceinline__ float fast_gelu(float x) {
    float x2 = x * x;
    float w  = x * __builtin_fmaf(0.1029456f, x2, 2.3022618f);
    w = fminf(w, 60.0f);
    float s = __builtin_amdgcn_exp2f(w);
    float r = __builtin_amdgcn_rcpf(s + 1.0f);
    return x * s * r;
}

// ---------------------------------------------------------------------------
// Persistent 256x256 GEMM, BK=32, 64KB LDS -> TWO blocks/CU (cross-block
// latency hiding: while one block's waves drain at a barrier, the other
// block's waves feed the MFMA pipe -- the m114 mechanism our 128KB variants
// forfeited at 1 block/CU). R9 phase skeleton unchanged:
//   phase = [stage 1 half-tile(u+1); ds_reads(this phase); (vmcnt); BAR;
//            lgkm0; setprio; MFMA cluster]
// Stage order B0@ph0, B1@ph1, A0@ph2, A1@ph3 (opposite parity only).
// vmcnt (1 gll per stage now):
//   ph1: outstanding = A1(u),B0(u+1),B1(u+1) -> vmcnt(2) drains A1(u)
//        before ph2's af45 (rows 128..191) reads.
//   ph3: outstanding = B0,B1,A0,A1(u+1) -> vmcnt(1) drains B0,B1,A0(u+1)
//        for next ph0's reads; A1(u+1) floats (guarded by next ph1 vmcnt).
// LDS 64KB: parity(bit15) | isB(bit14) | A: rows 0..255 x 64B.
// Swizzle (64B rows, 4 x 16B slots): phys slot = logical ^ ((row>>1)&3);
// staging source pre-swizzle c = (lane&3) ^ ((lane>>3)&3)  [row&7>>1 == lane>>3
// since srow = wid*16 + (lane>>2)]. Uniform 8 words/bank (capacity floor).
// ---------------------------------------------------------------------------
template <bool GELU_OUT, int LG_NT, int LG_TN, int LG_NTILE, int KDIM, int NDIM>
__global__ __launch_bounds__(512, 2) void gemm256(const bf16_t* __restrict__ Am,
                                                  const bf16_t* __restrict__ Bm,
                                                  const float* __restrict__ bias,
                                                  void* __restrict__ Cout) {
    extern __shared__ char lds[];
    constexpr int NT    = 1 << LG_NT;      // K-tiles per output tile (KDIM/32)
    constexpr int ntile = 1 << LG_NTILE;   // output tiles per block
    constexpr int U     = ntile << LG_NT;  // total flat K-iterations

    const int tid  = threadIdx.x;
    const int lane = tid & 63;
    const int wid  = tid >> 6;
    const int wr   = wid >> 2;   // 0..1
    const int wc   = wid & 3;    // 0..3

    // XCD-aware bijective swizzle over the fixed 512-block grid (q = 64)
    const int wgb = (blockIdx.x & 7) * 64 + (blockIdx.x >> 3);
    const int g0  = wgb << LG_NTILE;

    // staging lane geometry: half-tile = 128 rows x 32 cols (8KB), 1 gll/thread.
    // row = wid*16 + (lane>>2); phys 16B-slot = lane&3;
    // pre-swizzled logical col slot c = (lane&3) ^ ((lane>>3)&3).
    const int srow  = wid * 16 + (lane >> 2);
    const int scol8 = ((lane & 3) ^ ((lane >> 3) & 3)) * 8;

    auto STAGE = [&](int isB, int half, int slot) {
        const int us  = (slot < U) ? slot : (U - 1);       // clamp tail (dummy)
        const int ti_ = us >> LG_NT;
        const int kt_ = us & (NT - 1);
        const int g_  = g0 + ti_;
        const size_t base_ = (size_t)(isB ? (g_ & ((1 << LG_TN) - 1)) : (g_ >> LG_TN)) << 8;
        // parity from UNCLAMPED slot -> dummies land in the dead buffer
        const unsigned reg_ = (unsigned)(((slot & 1) << 15) | (isB << 14) | (half << 13));
        const bf16_t* s0 = (isB ? Bm : Am)
                         + (base_ + (size_t)(half * 128 + srow)) * (size_t)KDIM
                         + (size_t)((kt_ << 5) + scol8);
        __builtin_amdgcn_global_load_lds(
            (const __attribute__((address_space(1))) void*)s0,
            (__attribute__((address_space(3))) void*)(lds + reg_ + (unsigned)(wid * 1024)),
            16, 0, 0);
    };

    // M-frag m of wave wr -> tile row (m>>1)*64 + wr*32 + (m&1)*16
    auto ldsA = [&](unsigned bufo, int m) -> bf16x8 {
        const int row  = (m >> 1) * 64 + wr * 32 + (m & 1) * 16 + (lane & 15);
        const int slot = (lane >> 4) ^ ((row >> 1) & 3);
        return *(const bf16x8*)(lds + bufo + row * 64 + slot * 16);
    };
    auto ldsB = [&](unsigned bufo, int n) -> bf16x8 {
        const int row  = wc * 64 + n * 16 + (lane & 15);
        const int slot = (lane >> 4) ^ ((row >> 1) & 3);
        return *(const bf16x8*)(lds + bufo + 16384 + row * 64 + slot * 16);
    };

    f32x4 acc[8][4] = {};

    // Prologue: stage slot 0 completely (4 gll), drain, publish.
    STAGE(1, 0, 0); STAGE(1, 1, 0); STAGE(0, 0, 0); STAGE(0, 1, 0);
    asm volatile("s_waitcnt vmcnt(0)" ::: "memory");
    __builtin_amdgcn_s_barrier();

    for (int ti = 0; ti < ntile; ++ti) {
        for (int t = 0; t < NT; ++t) {
            const int u = (ti << LG_NT) + t;
            const unsigned cur = (unsigned)(t & 1) * 32768u;   // == (u&1), NT even
            bf16x8 bf[4];
            bf16x8 af[2];

            // ---- ph0: stage B0(u+1); read bf0..3 + af01; MFMA m01 ----
            STAGE(1, 0, u + 1);
#pragma unroll
            for (int n = 0; n < 4; ++n)
                bf[n] = ldsB(cur, n);
            af[0] = ldsA(cur, 0);
            af[1] = ldsA(cur, 1);
            __builtin_amdgcn_s_barrier();
            asm volatile("s_waitcnt lgkmcnt(0)" ::: "memory");
            __builtin_amdgcn_s_setprio(1);
#pragma unroll
            for (int mm = 0; mm < 2; ++mm)
#pragma unroll
                for (int n = 0; n < 4; ++n)
                    acc[mm][n] = __builtin_amdgcn_mfma_f32_16x16x32_bf16(
                        af[mm], bf[n], acc[mm][n], 0, 0, 0);
            __builtin_amdgcn_s_setprio(0);

            // ---- ph1: stage B1(u+1); read af23; vmcnt(2); MFMA m23 ----
            STAGE(1, 1, u + 1);
            af[0] = ldsA(cur, 2);
            af[1] = ldsA(cur, 3);
            asm volatile("s_waitcnt vmcnt(2)" ::: "memory");   // A1(u) landed
            __builtin_amdgcn_s_barrier();
            asm volatile("s_waitcnt lgkmcnt(0)" ::: "memory");
            __builtin_amdgcn_s_setprio(1);
#pragma unroll
            for (int mm = 0; mm < 2; ++mm)
#pragma unroll
                for (int n = 0; n < 4; ++n)
                    acc[2 + mm][n] = __builtin_amdgcn_mfma_f32_16x16x32_bf16(
                        af[mm], bf[n], acc[2 + mm][n], 0, 0, 0);
            __builtin_amdgcn_s_setprio(0);

            // ---- ph2: stage A0(u+1); read af45; MFMA m45 ----
            STAGE(0, 0, u + 1);
            af[0] = ldsA(cur, 4);
            af[1] = ldsA(cur, 5);
            __builtin_amdgcn_s_barrier();
            asm volatile("s_waitcnt lgkmcnt(0)" ::: "memory");
            __builtin_amdgcn_s_setprio(1);
#pragma unroll
            for (int mm = 0; mm < 2; ++mm)
#pragma unroll
                for (int n = 0; n < 4; ++n)
                    acc[4 + mm][n] = __builtin_amdgcn_mfma_f32_16x16x32_bf16(
                        af[mm], bf[n], acc[4 + mm][n], 0, 0, 0);
            __builtin_amdgcn_s_setprio(0);

            // ---- ph3: stage A1(u+1); read af67; vmcnt(1); MFMA m67 ----
            STAGE(0, 1, u + 1);
            af[0] = ldsA(cur, 6);
            af[1] = ldsA(cur, 7);
            asm volatile("s_waitcnt vmcnt(1)" ::: "memory");   // B0,B1,A0(u+1) landed
            __builtin_amdgcn_s_barrier();
            asm volatile("s_waitcnt lgkmcnt(0)" ::: "memory");
            __builtin_amdgcn_s_setprio(1);
#pragma unroll
            for (int mm = 0; mm < 2; ++mm)
#pragma unroll
                for (int n = 0; n < 4; ++n)
                    acc[6 + mm][n] = __builtin_amdgcn_mfma_f32_16x16x32_bf16(
                        af[mm], bf[n], acc[6 + mm][n], 0, 0, 0);
            __builtin_amdgcn_s_setprio(0);
        }

        // ---- per-tile epilogue (reg-only, no LDS; no extra barrier needed) ----
        const int g = g0 + ti;
        const size_t rowBase = (size_t)(g >> LG_TN) << 8;
        const size_t colBase = (size_t)(g & ((1 << LG_TN) - 1)) << 8;
        const int orow = (lane >> 4) * 4;
        const int ocol = lane & 15;
#pragma unroll
        for (int m = 0; m < 8; ++m) {
            const size_t rb = rowBase + (size_t)((m >> 1) * 64 + wr * 32 + (m & 1) * 16 + orow);
#pragma unroll
            for (int n = 0; n < 4; ++n) {
                const size_t col = colBase + (size_t)(wc * 64 + n * 16 + ocol);
                const float bv = bias[col];
#pragma unroll
                for (int j = 0; j < 4; ++j) {
                    float v = acc[m][n][j] + bv;
                    if constexpr (GELU_OUT) {
                        ((bf16_t*)Cout)[(rb + j) * (size_t)NDIM + col] = (bf16_t)fast_gelu(v);
                    } else {
                        ((float*)Cout)[(rb + j) * (size_t)NDIM + col] = v;
                    }
                }
                acc[m][n] = (f32x4){0.f, 0.f, 0.f, 0.f};
            }
        }
    }
    asm volatile("s_waitcnt vmcnt(0)" ::: "memory");   // drain tail dummy loads
}

// ---------------------------------------------------------------------------
extern "C" void kernel_launch(void* const* d_in, const int* in_sizes, int n_in,
                              void* d_out, int out_size, void* d_ws, size_t ws_size,
                              hipStream_t stream) {
    const float* x  = (const float*)d_in[0];  // [16384, 2048]
    const float* p1 = (const float*)d_in[1];  // [8192, 2048]
    const float* b1 = (const float*)d_in[2];  // [8192]
    const float* p2 = (const float*)d_in[3];  // [2048, 8192]
    const float* b2 = (const float*)d_in[4];  // [2048]
    // d_in[5] = gate_w, unused (routing is identity on the output)
    float* out = (float*)d_out;

    char* ws = (char*)d_ws;
    bf16_t* xb  = (bf16_t*)(ws);                          // 64 MB
    bf16_t* p1b = (bf16_t*)(ws + ((size_t)64 << 20));     // 32 MB
    bf16_t* p2b = (bf16_t*)(ws + ((size_t)96 << 20));     // 32 MB
    bf16_t* h   = (bf16_t*)(ws + ((size_t)128 << 20));    // 256 MB

    // GEMM1: [T,E] x [H,E]^T -> h.  2048 tiles = 512 blocks x 4 tiles.
    // NT = 2048/32 = 64 (lg 6), nTn = 8192/256 = 32 (lg 5), ntile = 4 (lg 2).
    auto g1 = gemm256<true, 6, 5, 2, E_DIM, H_DIM>;
    // GEMM2: [T,H] x [E,H]^T -> out. 512 tiles = 512 blocks x 1 tile.
    // NT = 8192/32 = 256 (lg 8), nTn = 2048/256 = 8 (lg 3), ntile = 1 (lg 0).
    auto g2 = gemm256<false, 8, 3, 0, H_DIM, E_DIM>;

    (void)hipFuncSetAttribute((const void*)g1,
                              hipFuncAttributeMaxDynamicSharedMemorySize, 65536);
    (void)hipFuncSetAttribute((const void*)g2,
                              hipFuncAttributeMaxDynamicSharedMemorySize, 65536);

    cvt_f32_bf16<<<2048, 256, 0, stream>>>(x,  xb,  (T_DIM * E_DIM) / 4);
    cvt_f32_bf16<<<1024, 256, 0, stream>>>(p1, p1b, (H_DIM * E_DIM) / 4);
    cvt_f32_bf16<<<1024, 256, 0, stream>>>(p2, p2b, (E_DIM * H_DIM) / 4);

    g1<<<512, 512, 65536, stream>>>(xb, p1b, b1, (void*)h);
    g2<<<512, 512, 65536, stream>>>(h, p2b, b2, (void*)out);
}

// Round 13
// 1015.756 us; speedup vs baseline: 2.7394x; 1.1067x over previous
//
#include <hip/hip_runtime.h>
#include <hip/hip_bf16.h>
#include <cstdint>
#include <cstddef>

typedef __bf16 bf16_t;
typedef __bf16 bf16x4 __attribute__((ext_vector_type(4)));
typedef __bf16 bf16x8 __attribute__((ext_vector_type(8)));
typedef float  f32x4  __attribute__((ext_vector_type(4)));

#define L_DIM 2048
#define N_DIM 8
#define E_DIM 2048
#define H_DIM 8192
#define T_DIM (L_DIM * N_DIM)   // 16384 tokens

// ---------------------------------------------------------------------------
__global__ __launch_bounds__(256) void cvt_f32_bf16(const float* __restrict__ in,
                                                    bf16_t* __restrict__ out,
                                                    int n4) {
    int stride = gridDim.x * blockDim.x;
    for (int i = blockIdx.x * blockDim.x + threadIdx.x; i < n4; i += stride) {
        float4 v = *(const float4*)(in + (size_t)i * 4);
        bf16x4 o;
        o[0] = (bf16_t)v.x; o[1] = (bf16_t)v.y;
        o[2] = (bf16_t)v.z; o[3] = (bf16_t)v.w;
        *(bf16x4*)(out + (size_t)i * 4) = o;
    }
}

// ---------------------------------------------------------------------------
__device__ __forceinline__ float fast_gelu(float x) {
    float x2 = x * x;
    float w  = x * __builtin_fmaf(0.1029456f, x2, 2.3022618f);
    w = fminf(w, 60.0f);
    float s = __builtin_amdgcn_exp2f(w);
    float r = __builtin_amdgcn_rcpf(s + 1.0f);
    return x * s * r;
}

// ---------------------------------------------------------------------------
// Persistent 256x256 GEMM, 2-barrier K-iter with WITHIN-INTERVAL overlap.
// R9 data path (staging geometry, LDS swizzle, parity discipline, XCD swizzle,
// persistence, epilogue) unchanged. Sync restructured: each K-iter = 2 barrier
// intervals; each interval runs TWO MFMA clusters, with the second cluster's
// A-reads issued AFTER the first cluster's MFMAs (they drain under MFMA
// execution -> within-wave read/MFMA overlap R9's [reads;BAR;lgkm0;MFMA]
// structure forbids). Read bursts stay small (<=12); no sched_barrier pins;
// no extra fragment double-buffering (R10/R11 failure modes avoided).
//   interval 1: RD bf+af01(12); STAGE B0,B1(u+1); lgkm0; m01;
//               RD af23(4); lgkm0; m23; vmcnt(4); BAR
//   interval 2: RD af45(4); STAGE A0,A1(u+1); lgkm0; m45;
//               RD af67(4); lgkm0; m67; vmcnt(2); BAR
// vmcnt derivation (2 gll per STAGE, in-order):
//   mid: outstanding = A1(u)[<=2] + B0,B1(u+1)[4] -> vmcnt(4) drains A1(u)
//        before interval 2 reads af45 (rows 128..191).
//   end: outstanding = B0,B1,A0,A1(u+1)[<=8] -> vmcnt(2) drains B0,B1,A0(u+1)
//        before next iter's bf/af01 reads; A1(u+1) floats (guarded at mid).
// WAR: all staging targets parity^1; all reads target parity -> disjoint for
// arbitrary intra-interval skew. Cross-iter reuse separated by 2 barriers.
// Epilogue stores inflate vmcnt only in the safe direction (over-wait).
// ---------------------------------------------------------------------------
template <bool GELU_OUT, int LG_NT, int LG_TN, int LG_NTILE, int KDIM, int NDIM>
__global__ __launch_bounds__(512, 2) void gemm256(const bf16_t* __restrict__ Am,
                                                  const bf16_t* __restrict__ Bm,
                                                  const float* __restrict__ bias,
                                                  void* __restrict__ Cout) {
    extern __shared__ char lds[];
    constexpr int NT    = 1 << LG_NT;      // K-tiles per output tile (KDIM/64)
    constexpr int ntile = 1 << LG_NTILE;   // output tiles per block
    constexpr int U     = ntile << LG_NT;  // total flat K-iterations

    const int tid  = threadIdx.x;
    const int lane = tid & 63;
    const int wid  = tid >> 6;
    const int wr   = wid >> 2;   // 0..1
    const int wc   = wid & 3;    // 0..3

    // XCD-aware bijective swizzle over the fixed 256-block grid (q = 32)
    const int wgb = (blockIdx.x & 7) * 32 + (blockIdx.x >> 3);
    const int g0  = wgb << LG_NTILE;

    // staging lane geometry: row_in_half = wid*8 + (lane>>3), phys slot = lane&7,
    // pre-swizzled logical col slot = (lane&7) ^ (row&7)  [row&7 == lane>>3]
    const int srow  = wid * 8 + (lane >> 3);
    const int scol8 = ((lane & 7) ^ (lane >> 3)) * 8;

    auto STAGE = [&](int isB, int half, int slot) {
        const int us  = (slot < U) ? slot : (U - 1);       // clamp tail (dummy)
        const int ti_ = us >> LG_NT;
        const int kt_ = us & (NT - 1);
        const int g_  = g0 + ti_;
        const size_t base_ = (size_t)(isB ? (g_ & ((1 << LG_TN) - 1)) : (g_ >> LG_TN)) << 8;
        // parity from UNCLAMPED slot -> dummies land in the dead buffer
        const unsigned reg_ = (unsigned)(((slot & 1) << 16) | (isB << 15) | (half << 14));
        const bf16_t* s0 = (isB ? Bm : Am)
                         + (base_ + (size_t)(half * 128 + srow)) * (size_t)KDIM
                         + (size_t)((kt_ << 6) + scol8);
        __builtin_amdgcn_global_load_lds(
            (const __attribute__((address_space(1))) void*)s0,
            (__attribute__((address_space(3))) void*)(lds + reg_ + (unsigned)(wid * 1024)),
            16, 0, 0);
        __builtin_amdgcn_global_load_lds(
            (const __attribute__((address_space(1))) void*)(s0 + (size_t)64 * KDIM),
            (__attribute__((address_space(3))) void*)(lds + reg_ + (unsigned)((8 + wid) * 1024)),
            16, 0, 0);
    };

    // M-frag m of wave wr -> tile row (m>>1)*64 + wr*32 + (m&1)*16
    auto ldsA = [&](unsigned bufo, int m, int kk) -> bf16x8 {
        const int row  = (m >> 1) * 64 + wr * 32 + (m & 1) * 16 + (lane & 15);
        const int slot = ((kk << 2) + (lane >> 4)) ^ (lane & 7);
        return *(const bf16x8*)(lds + bufo + row * 128 + slot * 16);
    };
    auto ldsB = [&](unsigned bufo, int n, int kk) -> bf16x8 {
        const int row  = wc * 64 + n * 16 + (lane & 15);
        const int slot = ((kk << 2) + (lane >> 4)) ^ (lane & 7);
        return *(const bf16x8*)(lds + bufo + 32768 + row * 128 + slot * 16);
    };

    f32x4 acc[8][4] = {};

    // Prologue: stage slot 0 completely, drain, publish.
    STAGE(1, 0, 0); STAGE(1, 1, 0); STAGE(0, 0, 0); STAGE(0, 1, 0);
    asm volatile("s_waitcnt vmcnt(0)" ::: "memory");
    __builtin_amdgcn_s_barrier();

    for (int ti = 0; ti < ntile; ++ti) {
        for (int t = 0; t < NT; ++t) {
            const int u = (ti << LG_NT) + t;
            const unsigned cur = (unsigned)(t & 1) * 65536u;   // == (u&1), NT even
            bf16x8 bf[4][2];
            bf16x8 af[2][2];

            // ========== interval 1 ==========
            // reads bf (8) + af01 (4); stage B0,B1(u+1)
#pragma unroll
            for (int n = 0; n < 4; ++n)
#pragma unroll
                for (int kk = 0; kk < 2; ++kk)
                    bf[n][kk] = ldsB(cur, n, kk);
#pragma unroll
            for (int mm = 0; mm < 2; ++mm)
#pragma unroll
                for (int kk = 0; kk < 2; ++kk)
                    af[mm][kk] = ldsA(cur, mm, kk);
            STAGE(1, 0, u + 1);
            STAGE(1, 1, u + 1);
            asm volatile("s_waitcnt lgkmcnt(0)" ::: "memory");
            __builtin_amdgcn_s_setprio(1);
#pragma unroll
            for (int mm = 0; mm < 2; ++mm)
#pragma unroll
                for (int n = 0; n < 4; ++n)
#pragma unroll
                    for (int kk = 0; kk < 2; ++kk)
                        acc[mm][n] = __builtin_amdgcn_mfma_f32_16x16x32_bf16(
                            af[mm][kk], bf[n][kk], acc[mm][n], 0, 0, 0);
            __builtin_amdgcn_s_setprio(0);
            // af23 issued after m01 -> drains under m01 execution
#pragma unroll
            for (int mm = 0; mm < 2; ++mm)
#pragma unroll
                for (int kk = 0; kk < 2; ++kk)
                    af[mm][kk] = ldsA(cur, 2 + mm, kk);
            asm volatile("s_waitcnt lgkmcnt(0)" ::: "memory");
            __builtin_amdgcn_s_setprio(1);
#pragma unroll
            for (int mm = 0; mm < 2; ++mm)
#pragma unroll
                for (int n = 0; n < 4; ++n)
#pragma unroll
                    for (int kk = 0; kk < 2; ++kk)
                        acc[2 + mm][n] = __builtin_amdgcn_mfma_f32_16x16x32_bf16(
                            af[mm][kk], bf[n][kk], acc[2 + mm][n], 0, 0, 0);
            __builtin_amdgcn_s_setprio(0);
            asm volatile("s_waitcnt vmcnt(4)" ::: "memory");   // A1(u) landed
            __builtin_amdgcn_s_barrier();

            // ========== interval 2 ==========
            // reads af45; stage A0,A1(u+1)
#pragma unroll
            for (int mm = 0; mm < 2; ++mm)
#pragma unroll
                for (int kk = 0; kk < 2; ++kk)
                    af[mm][kk] = ldsA(cur, 4 + mm, kk);
            STAGE(0, 0, u + 1);
            STAGE(0, 1, u + 1);
            asm volatile("s_waitcnt lgkmcnt(0)" ::: "memory");
            __builtin_amdgcn_s_setprio(1);
#pragma unroll
            for (int mm = 0; mm < 2; ++mm)
#pragma unroll
                for (int n = 0; n < 4; ++n)
#pragma unroll
                    for (int kk = 0; kk < 2; ++kk)
                        acc[4 + mm][n] = __builtin_amdgcn_mfma_f32_16x16x32_bf16(
                            af[mm][kk], bf[n][kk], acc[4 + mm][n], 0, 0, 0);
            __builtin_amdgcn_s_setprio(0);
            // af67 issued after m45 -> drains under m45 execution
#pragma unroll
            for (int mm = 0; mm < 2; ++mm)
#pragma unroll
                for (int kk = 0; kk < 2; ++kk)
                    af[mm][kk] = ldsA(cur, 6 + mm, kk);
            asm volatile("s_waitcnt lgkmcnt(0)" ::: "memory");
            __builtin_amdgcn_s_setprio(1);
#pragma unroll
            for (int mm = 0; mm < 2; ++mm)
#pragma unroll
                for (int n = 0; n < 4; ++n)
#pragma unroll
                    for (int kk = 0; kk < 2; ++kk)
                        acc[6 + mm][n] = __builtin_amdgcn_mfma_f32_16x16x32_bf16(
                            af[mm][kk], bf[n][kk], acc[6 + mm][n], 0, 0, 0);
            __builtin_amdgcn_s_setprio(0);
            asm volatile("s_waitcnt vmcnt(2)" ::: "memory");   // B0,B1,A0(u+1) landed
            __builtin_amdgcn_s_barrier();
        }

        // ---- per-tile epilogue (reg-only, no LDS; between BARs) ----
        const int g = g0 + ti;
        const size_t rowBase = (size_t)(g >> LG_TN) << 8;
        const size_t colBase = (size_t)(g & ((1 << LG_TN) - 1)) << 8;
        const int orow = (lane >> 4) * 4;
        const int ocol = lane & 15;
#pragma unroll
        for (int m = 0; m < 8; ++m) {
            const size_t rb = rowBase + (size_t)((m >> 1) * 64 + wr * 32 + (m & 1) * 16 + orow);
#pragma unroll
            for (int n = 0; n < 4; ++n) {
                const size_t col = colBase + (size_t)(wc * 64 + n * 16 + ocol);
                const float bv = bias[col];
#pragma unroll
                for (int j = 0; j < 4; ++j) {
                    float v = acc[m][n][j] + bv;
                    if constexpr (GELU_OUT) {
                        ((bf16_t*)Cout)[(rb + j) * (size_t)NDIM + col] = (bf16_t)fast_gelu(v);
                    } else {
                        ((float*)Cout)[(rb + j) * (size_t)NDIM + col] = v;
                    }
                }
                acc[m][n] = (f32x4){0.f, 0.f, 0.f, 0.f};
            }
        }
    }
    asm volatile("s_waitcnt vmcnt(0)" ::: "memory");   // drain tail dummy loads
}

// ---------------------------------------------------------------------------
extern "C" void kernel_launch(void* const* d_in, const int* in_sizes, int n_in,
                              void* d_out, int out_size, void* d_ws, size_t ws_size,
                              hipStream_t stream) {
    const float* x  = (const float*)d_in[0];  // [16384, 2048]
    const float* p1 = (const float*)d_in[1];  // [8192, 2048]
    const float* b1 = (const float*)d_in[2];  // [8192]
    const float* p2 = (const float*)d_in[3];  // [2048, 8192]
    const float* b2 = (const float*)d_in[4];  // [2048]
    // d_in[5] = gate_w, unused (routing is identity on the output)
    float* out = (float*)d_out;

    char* ws = (char*)d_ws;
    bf16_t* xb  = (bf16_t*)(ws);                          // 64 MB
    bf16_t* p1b = (bf16_t*)(ws + ((size_t)64 << 20));     // 32 MB
    bf16_t* p2b = (bf16_t*)(ws + ((size_t)96 << 20));     // 32 MB
    bf16_t* h   = (bf16_t*)(ws + ((size_t)128 << 20));    // 256 MB

    // GEMM1: [T,E] x [H,E]^T -> h.  2048 tiles = 256 blocks x 8 tiles.
    auto g1 = gemm256<true, 5, 5, 3, E_DIM, H_DIM>;
    // GEMM2: [T,H] x [E,H]^T -> out. 512 tiles = 256 blocks x 2 tiles.
    auto g2 = gemm256<false, 7, 3, 1, H_DIM, E_DIM>;

    (void)hipFuncSetAttribute((const void*)g1,
                              hipFuncAttributeMaxDynamicSharedMemorySize, 131072);
    (void)hipFuncSetAttribute((const void*)g2,
                              hipFuncAttributeMaxDynamicSharedMemorySize, 131072);

    cvt_f32_bf16<<<2048, 256, 0, stream>>>(x,  xb,  (T_DIM * E_DIM) / 4);
    cvt_f32_bf16<<<1024, 256, 0, stream>>>(p1, p1b, (H_DIM * E_DIM) / 4);
    cvt_f32_bf16<<<1024, 256, 0, stream>>>(p2, p2b, (E_DIM * H_DIM) / 4);

    g1<<<256, 512, 131072, stream>>>(xb, p1b, b1, (void*)h);
    g2<<<256, 512, 131072, stream>>>(h, p2b, b2, (void*)out);
}

// Round 14
// 1012.085 us; speedup vs baseline: 2.7493x; 1.0036x over previous
//
#include <hip/hip_runtime.h>
#include <hip/hip_bf16.h>
#include <cstdint>
#include <cstddef>

typedef __bf16 bf16_t;
typedef __bf16 bf16x4 __attribute__((ext_vector_type(4)));
typedef __bf16 bf16x8 __attribute__((ext_vector_type(8)));
typedef float  f32x4  __attribute__((ext_vector_type(4)));

#define L_DIM 2048
#define N_DIM 8
#define E_DIM 2048
#define H_DIM 8192
#define T_DIM (L_DIM * N_DIM)   // 16384 tokens

// ---------------------------------------------------------------------------
__global__ __launch_bounds__(256) void cvt_f32_bf16(const float* __restrict__ in,
                                                    bf16_t* __restrict__ out,
                                                    int n4) {
    int stride = gridDim.x * blockDim.x;
    for (int i = blockIdx.x * blockDim.x + threadIdx.x; i < n4; i += stride) {
        float4 v = *(const float4*)(in + (size_t)i * 4);
        bf16x4 o;
        o[0] = (bf16_t)v.x; o[1] = (bf16_t)v.y;
        o[2] = (bf16_t)v.z; o[3] = (bf16_t)v.w;
        *(bf16x4*)(out + (size_t)i * 4) = o;
    }
}

// ---------------------------------------------------------------------------
__device__ __forceinline__ float fast_gelu(float x) {
    float x2 = x * x;
    float w  = x * __builtin_fmaf(0.1029456f, x2, 2.3022618f);
    w = fminf(w, 60.0f);
    float s = __builtin_amdgcn_exp2f(w);
    float r = __builtin_amdgcn_rcpf(s + 1.0f);
    return x * s * r;
}

// ---------------------------------------------------------------------------
// KERNEL A (for GEMM1): persistent 256x256, 2-barrier K-iter with
// within-interval overlap (R13 structure, best measured for K=2048).
// ---------------------------------------------------------------------------
template <bool GELU_OUT, int LG_NT, int LG_TN, int LG_NTILE, int KDIM, int NDIM>
__global__ __launch_bounds__(512, 2) void gemm256(const bf16_t* __restrict__ Am,
                                                  const bf16_t* __restrict__ Bm,
                                                  const float* __restrict__ bias,
                                                  void* __restrict__ Cout) {
    extern __shared__ char lds[];
    constexpr int NT    = 1 << LG_NT;
    constexpr int ntile = 1 << LG_NTILE;
    constexpr int U     = ntile << LG_NT;

    const int tid  = threadIdx.x;
    const int lane = tid & 63;
    const int wid  = tid >> 6;
    const int wr   = wid >> 2;
    const int wc   = wid & 3;

    const int wgb = (blockIdx.x & 7) * 32 + (blockIdx.x >> 3);
    const int g0  = wgb << LG_NTILE;

    const int srow  = wid * 8 + (lane >> 3);
    const int scol8 = ((lane & 7) ^ (lane >> 3)) * 8;

    auto STAGE = [&](int isB, int half, int slot) {
        const int us  = (slot < U) ? slot : (U - 1);
        const int ti_ = us >> LG_NT;
        const int kt_ = us & (NT - 1);
        const int g_  = g0 + ti_;
        const size_t base_ = (size_t)(isB ? (g_ & ((1 << LG_TN) - 1)) : (g_ >> LG_TN)) << 8;
        const unsigned reg_ = (unsigned)(((slot & 1) << 16) | (isB << 15) | (half << 14));
        const bf16_t* s0 = (isB ? Bm : Am)
                         + (base_ + (size_t)(half * 128 + srow)) * (size_t)KDIM
                         + (size_t)((kt_ << 6) + scol8);
        __builtin_amdgcn_global_load_lds(
            (const __attribute__((address_space(1))) void*)s0,
            (__attribute__((address_space(3))) void*)(lds + reg_ + (unsigned)(wid * 1024)),
            16, 0, 0);
        __builtin_amdgcn_global_load_lds(
            (const __attribute__((address_space(1))) void*)(s0 + (size_t)64 * KDIM),
            (__attribute__((address_space(3))) void*)(lds + reg_ + (unsigned)((8 + wid) * 1024)),
            16, 0, 0);
    };

    auto ldsA = [&](unsigned bufo, int m, int kk) -> bf16x8 {
        const int row  = (m >> 1) * 64 + wr * 32 + (m & 1) * 16 + (lane & 15);
        const int slot = ((kk << 2) + (lane >> 4)) ^ (lane & 7);
        return *(const bf16x8*)(lds + bufo + row * 128 + slot * 16);
    };
    auto ldsB = [&](unsigned bufo, int n, int kk) -> bf16x8 {
        const int row  = wc * 64 + n * 16 + (lane & 15);
        const int slot = ((kk << 2) + (lane >> 4)) ^ (lane & 7);
        return *(const bf16x8*)(lds + bufo + 32768 + row * 128 + slot * 16);
    };

    f32x4 acc[8][4] = {};

    STAGE(1, 0, 0); STAGE(1, 1, 0); STAGE(0, 0, 0); STAGE(0, 1, 0);
    asm volatile("s_waitcnt vmcnt(0)" ::: "memory");
    __builtin_amdgcn_s_barrier();

    for (int ti = 0; ti < ntile; ++ti) {
        for (int t = 0; t < NT; ++t) {
            const int u = (ti << LG_NT) + t;
            const unsigned cur = (unsigned)(t & 1) * 65536u;
            bf16x8 bf[4][2];
            bf16x8 af[2][2];

            // ========== interval 1 ==========
#pragma unroll
            for (int n = 0; n < 4; ++n)
#pragma unroll
                for (int kk = 0; kk < 2; ++kk)
                    bf[n][kk] = ldsB(cur, n, kk);
#pragma unroll
            for (int mm = 0; mm < 2; ++mm)
#pragma unroll
                for (int kk = 0; kk < 2; ++kk)
                    af[mm][kk] = ldsA(cur, mm, kk);
            STAGE(1, 0, u + 1);
            STAGE(1, 1, u + 1);
            asm volatile("s_waitcnt lgkmcnt(0)" ::: "memory");
            __builtin_amdgcn_s_setprio(1);
#pragma unroll
            for (int mm = 0; mm < 2; ++mm)
#pragma unroll
                for (int n = 0; n < 4; ++n)
#pragma unroll
                    for (int kk = 0; kk < 2; ++kk)
                        acc[mm][n] = __builtin_amdgcn_mfma_f32_16x16x32_bf16(
                            af[mm][kk], bf[n][kk], acc[mm][n], 0, 0, 0);
            __builtin_amdgcn_s_setprio(0);
#pragma unroll
            for (int mm = 0; mm < 2; ++mm)
#pragma unroll
                for (int kk = 0; kk < 2; ++kk)
                    af[mm][kk] = ldsA(cur, 2 + mm, kk);
            asm volatile("s_waitcnt lgkmcnt(0)" ::: "memory");
            __builtin_amdgcn_s_setprio(1);
#pragma unroll
            for (int mm = 0; mm < 2; ++mm)
#pragma unroll
                for (int n = 0; n < 4; ++n)
#pragma unroll
                    for (int kk = 0; kk < 2; ++kk)
                        acc[2 + mm][n] = __builtin_amdgcn_mfma_f32_16x16x32_bf16(
                            af[mm][kk], bf[n][kk], acc[2 + mm][n], 0, 0, 0);
            __builtin_amdgcn_s_setprio(0);
            asm volatile("s_waitcnt vmcnt(4)" ::: "memory");
            __builtin_amdgcn_s_barrier();

            // ========== interval 2 ==========
#pragma unroll
            for (int mm = 0; mm < 2; ++mm)
#pragma unroll
                for (int kk = 0; kk < 2; ++kk)
                    af[mm][kk] = ldsA(cur, 4 + mm, kk);
            STAGE(0, 0, u + 1);
            STAGE(0, 1, u + 1);
            asm volatile("s_waitcnt lgkmcnt(0)" ::: "memory");
            __builtin_amdgcn_s_setprio(1);
#pragma unroll
            for (int mm = 0; mm < 2; ++mm)
#pragma unroll
                for (int n = 0; n < 4; ++n)
#pragma unroll
                    for (int kk = 0; kk < 2; ++kk)
                        acc[4 + mm][n] = __builtin_amdgcn_mfma_f32_16x16x32_bf16(
                            af[mm][kk], bf[n][kk], acc[4 + mm][n], 0, 0, 0);
            __builtin_amdgcn_s_setprio(0);
#pragma unroll
            for (int mm = 0; mm < 2; ++mm)
#pragma unroll
                for (int kk = 0; kk < 2; ++kk)
                    af[mm][kk] = ldsA(cur, 6 + mm, kk);
            asm volatile("s_waitcnt lgkmcnt(0)" ::: "memory");
            __builtin_amdgcn_s_setprio(1);
#pragma unroll
            for (int mm = 0; mm < 2; ++mm)
#pragma unroll
                for (int n = 0; n < 4; ++n)
#pragma unroll
                    for (int kk = 0; kk < 2; ++kk)
                        acc[6 + mm][n] = __builtin_amdgcn_mfma_f32_16x16x32_bf16(
                            af[mm][kk], bf[n][kk], acc[6 + mm][n], 0, 0, 0);
            __builtin_amdgcn_s_setprio(0);
            asm volatile("s_waitcnt vmcnt(2)" ::: "memory");
            __builtin_amdgcn_s_barrier();
        }

        const int g = g0 + ti;
        const size_t rowBase = (size_t)(g >> LG_TN) << 8;
        const size_t colBase = (size_t)(g & ((1 << LG_TN) - 1)) << 8;
        const int orow = (lane >> 4) * 4;
        const int ocol = lane & 15;
#pragma unroll
        for (int m = 0; m < 8; ++m) {
            const size_t rb = rowBase + (size_t)((m >> 1) * 64 + wr * 32 + (m & 1) * 16 + orow);
#pragma unroll
            for (int n = 0; n < 4; ++n) {
                const size_t col = colBase + (size_t)(wc * 64 + n * 16 + ocol);
                const float bv = bias[col];
#pragma unroll
                for (int j = 0; j < 4; ++j) {
                    float v = acc[m][n][j] + bv;
                    if constexpr (GELU_OUT) {
                        ((bf16_t*)Cout)[(rb + j) * (size_t)NDIM + col] = (bf16_t)fast_gelu(v);
                    } else {
                        ((float*)Cout)[(rb + j) * (size_t)NDIM + col] = v;
                    }
                }
                acc[m][n] = (f32x4){0.f, 0.f, 0.f, 0.f};
            }
        }
    }
    asm volatile("s_waitcnt vmcnt(0)" ::: "memory");
}

// ---------------------------------------------------------------------------
// KERNEL B (for GEMM2): non-persistent 256x256 8-phase m201-style schedule
// with deep vmcnt(6) prefetch cushion (R3 artifact verbatim; best measured
// for the K=8192 GEMM). One output tile per block.
// ---------------------------------------------------------------------------
template <bool GELU_OUT>
__global__ __launch_bounds__(512, 2) void gemm256_p8(const bf16_t* __restrict__ Am,
                                                     const bf16_t* __restrict__ Bm,
                                                     const float* __restrict__ bias,
                                                     void* __restrict__ Cout,
                                                     int M, int N, int K) {
    extern __shared__ char lds[];
    const int NT = K / 64;

    const int tid  = threadIdx.x;
    const int lane = tid & 63;
    const int wid  = tid >> 6;
    const int wr   = wid >> 2;
    const int wc   = wid & 3;

    const int nTn = N / 256;
    const int nwg = (M / 256) * nTn;
    const int q   = nwg >> 3;
    const int wg  = (blockIdx.x & 7) * q + (blockIdx.x >> 3);
    const size_t rowBase = (size_t)(wg / nTn) * 256;
    const size_t colBase = (size_t)(wg % nTn) * 256;

    const int srow  = wid * 8 + (lane >> 3);
    const int scol8 = ((lane & 7) ^ (lane >> 3)) * 8;

    auto STAGE = [&](int isB, int half, int slot) {
        const int kt_ = (slot < NT) ? slot : (NT - 1);
        const unsigned reg_ = (unsigned)((slot & 1) * 65536 + isB * 32768 + half * 16384);
        const bf16_t* gbase_ = isB ? Bm : Am;
        const size_t gr_ = (isB ? colBase : rowBase) + (size_t)(half * 128 + srow);
        const bf16_t* s0 = gbase_ + gr_ * (size_t)K + (size_t)(kt_ * 64 + scol8);
        __builtin_amdgcn_global_load_lds(
            (const __attribute__((address_space(1))) void*)s0,
            (__attribute__((address_space(3))) void*)(lds + reg_ + (unsigned)(wid * 1024)),
            16, 0, 0);
        __builtin_amdgcn_global_load_lds(
            (const __attribute__((address_space(1))) void*)(s0 + (size_t)64 * K),
            (__attribute__((address_space(3))) void*)(lds + reg_ + (unsigned)((8 + wid) * 1024)),
            16, 0, 0);
    };

    auto ldsA = [&](unsigned bufo, int m, int kk) -> bf16x8 {
        const int row  = (m >> 1) * 64 + wr * 32 + (m & 1) * 16 + (lane & 15);
        const int slot = ((kk << 2) + (lane >> 4)) ^ (lane & 7);
        return *(const bf16x8*)(lds + bufo + row * 128 + slot * 16);
    };
    auto ldsB = [&](unsigned bufo, int n, int kk) -> bf16x8 {
        const int row  = wc * 64 + n * 16 + (lane & 15);
        const int slot = ((kk << 2) + (lane >> 4)) ^ (lane & 7);
        return *(const bf16x8*)(lds + bufo + 32768 + row * 128 + slot * 16);
    };

    f32x4 acc[8][4] = {};

    STAGE(1, 0, 0); STAGE(1, 1, 0); STAGE(0, 0, 0); STAGE(0, 1, 0);
    STAGE(1, 0, 1); STAGE(1, 1, 1); STAGE(0, 0, 1);
    asm volatile("s_waitcnt vmcnt(6)" ::: "memory");
    __builtin_amdgcn_s_barrier();

    for (int t = 0; t < NT; ++t) {
        const unsigned cur = (unsigned)(t & 1) * 65536u;
        bf16x8 bf[4][2];
        bf16x8 af[2][2];

#pragma unroll
        for (int n = 0; n < 4; ++n)
#pragma unroll
            for (int kk = 0; kk < 2; ++kk)
                bf[n][kk] = ldsB(cur, n, kk);
#pragma unroll
        for (int mm = 0; mm < 2; ++mm)
#pragma unroll
            for (int kk = 0; kk < 2; ++kk)
                af[mm][kk] = ldsA(cur, mm, kk);
        STAGE(0, 1, t + 1);
        asm volatile("s_waitcnt lgkmcnt(8)" ::: "memory");
        __builtin_amdgcn_s_barrier();
        asm volatile("s_waitcnt lgkmcnt(0)" ::: "memory");
        __builtin_amdgcn_s_setprio(1);
#pragma unroll
        for (int mm = 0; mm < 2; ++mm)
#pragma unroll
            for (int n = 0; n < 4; ++n)
#pragma unroll
                for (int kk = 0; kk < 2; ++kk)
                    acc[mm][n] = __builtin_amdgcn_mfma_f32_16x16x32_bf16(
                        af[mm][kk], bf[n][kk], acc[mm][n], 0, 0, 0);
        __builtin_amdgcn_s_setprio(0);
        __builtin_amdgcn_s_barrier();

#pragma unroll
        for (int ph = 1; ph < 4; ++ph) {
#pragma unroll
            for (int mm = 0; mm < 2; ++mm)
#pragma unroll
                for (int kk = 0; kk < 2; ++kk)
                    af[mm][kk] = ldsA(cur, ph * 2 + mm, kk);
            if (ph == 1)      STAGE(1, 0, t + 2);
            else if (ph == 2) STAGE(1, 1, t + 2);
            else {            STAGE(0, 0, t + 2);
                              asm volatile("s_waitcnt vmcnt(6)" ::: "memory"); }
            __builtin_amdgcn_s_barrier();
            asm volatile("s_waitcnt lgkmcnt(0)" ::: "memory");
            __builtin_amdgcn_s_setprio(1);
#pragma unroll
            for (int mm = 0; mm < 2; ++mm)
#pragma unroll
                for (int n = 0; n < 4; ++n)
#pragma unroll
                    for (int kk = 0; kk < 2; ++kk)
                        acc[ph * 2 + mm][n] = __builtin_amdgcn_mfma_f32_16x16x32_bf16(
                            af[mm][kk], bf[n][kk], acc[ph * 2 + mm][n], 0, 0, 0);
            __builtin_amdgcn_s_setprio(0);
            __builtin_amdgcn_s_barrier();
        }
    }
    asm volatile("s_waitcnt vmcnt(0)" ::: "memory");

    const int orow = (lane >> 4) * 4;
    const int ocol = lane & 15;
#pragma unroll
    for (int m = 0; m < 8; ++m) {
        const size_t rb = rowBase + (size_t)((m >> 1) * 64 + wr * 32 + (m & 1) * 16 + orow);
#pragma unroll
        for (int n = 0; n < 4; ++n) {
            const size_t col = colBase + (size_t)(wc * 64 + n * 16 + ocol);
            const float bv = bias[col];
#pragma unroll
            for (int j = 0; j < 4; ++j) {
                float v = acc[m][n][j] + bv;
                if constexpr (GELU_OUT) {
                    ((bf16_t*)Cout)[(rb + j) * (size_t)N + col] = (bf16_t)fast_gelu(v);
                } else {
                    ((float*)Cout)[(rb + j) * (size_t)N + col] = v;
                }
            }
        }
    }
}

// ---------------------------------------------------------------------------
extern "C" void kernel_launch(void* const* d_in, const int* in_sizes, int n_in,
                              void* d_out, int out_size, void* d_ws, size_t ws_size,
                              hipStream_t stream) {
    const float* x  = (const float*)d_in[0];  // [16384, 2048]
    const float* p1 = (const float*)d_in[1];  // [8192, 2048]
    const float* b1 = (const float*)d_in[2];  // [8192]
    const float* p2 = (const float*)d_in[3];  // [2048, 8192]
    const float* b2 = (const float*)d_in[4];  // [2048]
    // d_in[5] = gate_w, unused (routing is identity on the output)
    float* out = (float*)d_out;

    char* ws = (char*)d_ws;
    bf16_t* xb  = (bf16_t*)(ws);                          // 64 MB
    bf16_t* p1b = (bf16_t*)(ws + ((size_t)64 << 20));     // 32 MB
    bf16_t* p2b = (bf16_t*)(ws + ((size_t)96 << 20));     // 32 MB
    bf16_t* h   = (bf16_t*)(ws + ((size_t)128 << 20));    // 256 MB

    // GEMM1 (K=2048): persistent R13 kernel. 2048 tiles = 256 blocks x 8.
    auto g1 = gemm256<true, 5, 5, 3, E_DIM, H_DIM>;
    // GEMM2 (K=8192): non-persistent m201-style 8-phase. 512 blocks x 1 tile.
    auto g2 = gemm256_p8<false>;

    (void)hipFuncSetAttribute((const void*)g1,
                              hipFuncAttributeMaxDynamicSharedMemorySize, 131072);
    (void)hipFuncSetAttribute((const void*)g2,
                              hipFuncAttributeMaxDynamicSharedMemorySize, 131072);

    cvt_f32_bf16<<<2048, 256, 0, stream>>>(x,  xb,  (T_DIM * E_DIM) / 4);
    cvt_f32_bf16<<<1024, 256, 0, stream>>>(p1, p1b, (H_DIM * E_DIM) / 4);
    cvt_f32_bf16<<<1024, 256, 0, stream>>>(p2, p2b, (E_DIM * H_DIM) / 4);

    g1<<<256, 512, 131072, stream>>>(xb, p1b, b1, (void*)h);
    g2<<<(T_DIM / 256) * (E_DIM / 256), 512, 131072, stream>>>(
        h, p2b, b2, (void*)out, T_DIM, E_DIM, H_DIM);
}